// Round 10
// baseline (103.566 us; speedup 1.0000x reference)
//
#include <hip/hip_runtime.h>
#include <hip/hip_bf16.h>

typedef unsigned short u16;
typedef __attribute__((ext_vector_type(8))) short short8;
typedef __attribute__((ext_vector_type(4))) float f32x4;
typedef __attribute__((ext_vector_type(16))) float f32x16;

#define MFMA32(a,b,c) __builtin_amdgcn_mfma_f32_32x32x16_bf16(a,b,c,0,0,0)
#define LGKM_BARRIER() asm volatile("s_waitcnt lgkmcnt(0)\n\ts_barrier" ::: "memory")

__device__ __forceinline__ u16 f2bf(float x){
  union { float f; unsigned u; } v; v.f = x;
  unsigned r = v.u + 0x7FFFu + ((v.u >> 16) & 1u);   // RTNE
  return (u16)(r >> 16);
}

__device__ __forceinline__ short8 pack8(float4 a, float4 b){
  short8 p;
  p[0]=(short)f2bf(a.x); p[1]=(short)f2bf(a.y); p[2]=(short)f2bf(a.z); p[3]=(short)f2bf(a.w);
  p[4]=(short)f2bf(b.x); p[5]=(short)f2bf(b.y); p[6]=(short)f2bf(b.z); p[7]=(short)f2bf(b.w);
  return p;
}

// =============== kPrep: W1-permute(32x32 frag) + W2 transpose + GEMM3 =====
// blocks 0..319   : W1 -> w1bp: elem j of gid=(kc*10+nt)*64+l holds
//                   W1[nt*32 + (l&31)][kc*16 + (l>>5)*8 + j]   (B frag order)
// blocks 320..639 : W2[1000][320] -> W2T[320][1024] zero-padded
// blocks 640..895 : l3p[kg(16)][64][1024] = feat @ W3^T split-K partials
__global__ __launch_bounds__(256) void kprep(
    const float* __restrict__ W1, const float* __restrict__ W2,
    const float* __restrict__ feat, const float* __restrict__ W3,
    u16* __restrict__ w1bp, float* __restrict__ W2T, float* __restrict__ l3p)
{
  __shared__ float tile[32][33];
  __shared__ __attribute__((aligned(16))) float At[32*68];
  __shared__ __attribute__((aligned(16))) float Bt[32*68];
  const int bid = blockIdx.x;
  const int t = threadIdx.x;

  if (bid < 320){
    int gid = bid * 256 + t;
    int l = gid & 63;
    int cn = gid >> 6;            // kc*10 + nt, 0..1279
    int kc = cn / 10;
    int nt = cn - kc * 10;
    int row = nt * 32 + (l & 31);
    int col = kc * 16 + (l >> 5) * 8;
    const float4* s = (const float4*)(W1 + (size_t)row * 2048 + col);
    *(short8*)(w1bp + (size_t)gid * 8) = pack8(s[0], s[1]);
  } else if (bid < 640){
    const int bb = bid - 320;
    const int tx = t & 31, ty = t >> 5;          // 32 x 8
    const int bx = bb & 31;                      // c tile (32 -> 1024)
    const int by = bb >> 5;                      // a tile (10 -> 320)
#pragma unroll
    for (int k = 0; k < 4; ++k){
      int c = bx*32 + ty + k*8;
      int a = by*32 + tx;
      tile[ty + k*8][tx] = (c < 1000) ? W2[(size_t)c*320 + a] : 0.f;
    }
    __syncthreads();
#pragma unroll
    for (int k = 0; k < 4; ++k){
      int a = by*32 + ty + k*8;
      int c = bx*32 + tx;
      W2T[(size_t)a*1024 + c] = tile[tx][ty + k*8];
    }
  } else {
    // ---- GEMM3: 64x64 C tile, K chunk 128 (4 stages of 32) ----
    const int bb = bid - 640;
    const int kg = bb & 15;              // K chunk of 128
    const int cg = bb >> 4;              // 16 c-groups of 64
    const int cbase = cg * 64;
    const int tm = t >> 4, tn = t & 15;  // 16x16 threads, 4x4 microtile
    const int sr = t >> 2, skc = (t & 3) * 8;  // staging: row, k-chunk
    f32x4 acc4[4];
#pragma unroll
    for (int i = 0; i < 4; ++i) acc4[i] = (f32x4){0.f,0.f,0.f,0.f};

    for (int st = 0; st < 4; ++st){
      const int kbase = kg*128 + st*32;
      {
        const float4* s = (const float4*)(feat + (size_t)sr*2048 + kbase + skc);
        float4 v0 = s[0], v1 = s[1];
        At[(skc+0)*68 + sr] = v0.x; At[(skc+1)*68 + sr] = v0.y;
        At[(skc+2)*68 + sr] = v0.z; At[(skc+3)*68 + sr] = v0.w;
        At[(skc+4)*68 + sr] = v1.x; At[(skc+5)*68 + sr] = v1.y;
        At[(skc+6)*68 + sr] = v1.z; At[(skc+7)*68 + sr] = v1.w;
      }
      {
        int c = cbase + sr;
        float4 v0 = {0,0,0,0}, v1 = {0,0,0,0};
        if (c < 1000){
          const float4* s = (const float4*)(W3 + (size_t)c*2048 + kbase + skc);
          v0 = s[0]; v1 = s[1];
        }
        Bt[(skc+0)*68 + sr] = v0.x; Bt[(skc+1)*68 + sr] = v0.y;
        Bt[(skc+2)*68 + sr] = v0.z; Bt[(skc+3)*68 + sr] = v0.w;
        Bt[(skc+4)*68 + sr] = v1.x; Bt[(skc+5)*68 + sr] = v1.y;
        Bt[(skc+6)*68 + sr] = v1.z; Bt[(skc+7)*68 + sr] = v1.w;
      }
      __syncthreads();
#pragma unroll
      for (int kk = 0; kk < 32; ++kk){
        f32x4 a = *(const f32x4*)(At + kk*68 + tm*4);
        f32x4 b = *(const f32x4*)(Bt + kk*68 + tn*4);
        acc4[0] += a[0] * b;
        acc4[1] += a[1] * b;
        acc4[2] += a[2] * b;
        acc4[3] += a[3] * b;
      }
      __syncthreads();
    }
#pragma unroll
    for (int i = 0; i < 4; ++i)
      *(f32x4*)(l3p + (size_t)kg*65536 + (tm*4+i)*1024 + cbase + tn*4) = acc4[i];
  }
}

// =============== K1: GEMM1 (32x32 MFMA) + softmax + region partials =======
// grid 392 (M=32), block 640 (10 waves). Wave wv owns n-cols [wv*32, wv*32+32).
// B: direct L2->reg (fragment-ordered w1bp, 4 x 1KB coalesced loads/iter).
// A: regs -> bf16 -> swizzled LDS dbuf (2 x 4KB). One lgkm barrier per iter.
__global__ __launch_bounds__(640, 5) void k1_main(
    const float* __restrict__ am, const u16* __restrict__ w1bp,
    float* __restrict__ partial)
{
  __shared__ __attribute__((aligned(16))) u16 sA[2][2048];  // 2 x 4 KB
  __shared__ float redM[32][10];
  __shared__ float redS[32][10];

  const int t = threadIdx.x;
  const int wv = t >> 6, l = t & 63;
  const int half = l >> 5;
  const int rA = l & 31;
  const int blk = blockIdx.x;

  f32x16 acc;
#pragma unroll
  for (int r = 0; r < 16; ++r) acc[r] = 0.f;

  // A staging (threads 0..511): row ar, float4 quad aq of each 64-k chunk
  const int ar = t >> 4, aq = t & 15;
  const float* aptr = am + (size_t)(blk*32 + ar)*2048 + aq*4;
  const int awb = ar*128 + (((aq>>1) ^ (ar & 7))*16) + (aq & 1)*8;

  // B fragment base: chunk c=(k*4+kc): byte (c*10 + wv)*1024 + l*16
  const char* const bb = (const char*)w1bp + (size_t)wv*1024 + (size_t)l*16;

  // A-frag read offsets (kc = 0..3): row rA, slot (kc*2+half) swizzled
  const int ab0 = rA*128 + (((0*2+half) ^ (rA & 7))*16);
  const int ab1 = rA*128 + (((1*2+half) ^ (rA & 7))*16);
  const int ab2 = rA*128 + (((2*2+half) ^ (rA & 7))*16);
  const int ab3 = rA*128 + (((3*2+half) ^ (rA & 7))*16);

  short8 Be0, Be1, Be2, Be3, Bo0, Bo1, Bo2, Bo3;
  float4 Se, So;

#define LDB(K, S0, S1, S2, S3)                                          \
  { const char* bp = bb + (size_t)(K)*40960;                            \
    S0 = *(const short8*)(bp);                                          \
    S1 = *(const short8*)(bp + 10240);                                  \
    S2 = *(const short8*)(bp + 20480);                                  \
    S3 = *(const short8*)(bp + 30720); }

#define DSW(BUF, S)                                                     \
  if (t < 512){                                                         \
    unsigned p0 = (unsigned)f2bf(S.x) | ((unsigned)f2bf(S.y) << 16);    \
    unsigned p1 = (unsigned)f2bf(S.z) | ((unsigned)f2bf(S.w) << 16);    \
    *(uint2*)((char*)&sA[BUF][0] + awb) = make_uint2(p0, p1);           \
  }

#define MFMA4(BUF, B0, B1, B2, B3)                                      \
  { const char* sac = (const char*)&sA[BUF][0];                         \
    short8 a0 = *(const short8*)(sac + ab0);                            \
    acc = MFMA32(a0, B0, acc);                                          \
    short8 a1 = *(const short8*)(sac + ab1);                            \
    acc = MFMA32(a1, B1, acc);                                          \
    short8 a2 = *(const short8*)(sac + ab2);                            \
    acc = MFMA32(a2, B2, acc);                                          \
    short8 a3 = *(const short8*)(sac + ab3);                            \
    acc = MFMA32(a3, B3, acc); }

  // ---------------- prologue ----------------
  if (t < 512){
    Se = *(const float4*)(aptr);          // A(0)
    So = *(const float4*)(aptr + 64);     // A(1)
  }
  DSW(0, Se);                             // A(0) -> sA[0]
  LDB(0, Be0, Be1, Be2, Be3);             // B(0)
  LGKM_BARRIER();

  // ---------------- steady: k = 0..29 (15 pairs) ----------------
#pragma unroll 1
  for (int k2 = 0; k2 < 15; ++k2){
    const int k = 2*k2;
    // even k: read sA[0]+Be, write A(k+1)=So -> sA[1], load A(k+2)->Se, B(k+1)->Bo
    if (t < 512) Se = *(const float4*)(aptr + (size_t)(k+2)*64);
    LDB(k+1, Bo0, Bo1, Bo2, Bo3);
    DSW(1, So);
    MFMA4(0, Be0, Be1, Be2, Be3);
    LGKM_BARRIER();
    // odd k+1: read sA[1]+Bo, write A(k+2)=Se -> sA[0], load A(k+3)->So, B(k+2)->Be
    if (t < 512) So = *(const float4*)(aptr + (size_t)(k+3)*64);
    LDB(k+2, Be0, Be1, Be2, Be3);
    DSW(0, Se);
    MFMA4(1, Bo0, Bo1, Bo2, Bo3);
    LGKM_BARRIER();
  }
  // ---------------- k = 30 ----------------
  LDB(31, Bo0, Bo1, Bo2, Bo3);
  DSW(1, So);                             // A(31) -> sA[1]
  MFMA4(0, Be0, Be1, Be2, Be3);
  LGKM_BARRIER();
  // ---------------- k = 31 ----------------
  MFMA4(1, Bo0, Bo1, Bo2, Bo3);

#undef LDB
#undef DSW
#undef MFMA4

  // ---- epilogue: softmax over 320 cols ----
  // C/D: col(n) = wv*32 + (l&31); row = (r&3) + 8*(r>>2) + 4*half
  {
    float rmx[16];
#pragma unroll
    for (int r = 0; r < 16; ++r){
      float x = acc[r];
      x = fmaxf(x, __shfl_xor(x, 1));
      x = fmaxf(x, __shfl_xor(x, 2));
      x = fmaxf(x, __shfl_xor(x, 4));
      x = fmaxf(x, __shfl_xor(x, 8));
      x = fmaxf(x, __shfl_xor(x, 16));
      rmx[r] = x;
    }
    if ((l & 31) == 0){
#pragma unroll
      for (int r = 0; r < 16; ++r)
        redM[(r&3) + 8*(r>>2) + 4*half][wv] = rmx[r];
    }
  }
  __syncthreads();
  if (wv == 0 && l < 32){
    float m = redM[l][0];
#pragma unroll
    for (int w2 = 1; w2 < 10; ++w2) m = fmaxf(m, redM[l][w2]);
    redM[l][0] = m;
  }
  __syncthreads();
  {
    float rsum[16];
#pragma unroll
    for (int r = 0; r < 16; ++r){
      int row = (r&3) + 8*(r>>2) + 4*half;
      float e = __expf(acc[r] - redM[row][0]);
      acc[r] = e;
      float s = e;
      s += __shfl_xor(s, 1);
      s += __shfl_xor(s, 2);
      s += __shfl_xor(s, 4);
      s += __shfl_xor(s, 8);
      s += __shfl_xor(s, 16);
      rsum[r] = s;
    }
    if ((l & 31) == 0){
#pragma unroll
      for (int r = 0; r < 16; ++r)
        redS[(r&3) + 8*(r>>2) + 4*half][wv] = rsum[r];
    }
  }
  __syncthreads();
  if (wv == 0 && l < 32){
    float s = 0.f;
#pragma unroll
    for (int w2 = 0; w2 < 10; ++w2) s += redS[l][w2];
    redS[l][0] = 1.f / s;
  }
  __syncthreads();
  {
    const int n0 = blk * 32;
    const int thr = 196 * (n0/196 + 1) - n0;   // rows < thr -> seg0
    float s0 = 0.f, s1 = 0.f;
#pragma unroll
    for (int r = 0; r < 16; ++r){
      int row = (r&3) + 8*(r>>2) + 4*half;
      float v = acc[r] * redS[row][0];
      if (row < thr) s0 += v; else s1 += v;
    }
    s0 += __shfl_xor(s0, 32);
    s1 += __shfl_xor(s1, 32);
    if (l < 32){
      partial[blk*640 +       wv*32 + l] = s0;
      partial[blk*640 + 320 + wv*32 + l] = s1;
    }
  }
}

// =============== K2c: reduce partials + attr_dis@W2T + both softmax =======
__global__ __launch_bounds__(256) void k2c_final(
    const float* __restrict__ partialp, const float* __restrict__ W2T,
    const float* __restrict__ l3p, float* __restrict__ outp,
    float* __restrict__ out_ad)
{
  __shared__ __attribute__((aligned(16))) float sad[320];
  __shared__ float redA[4], redB[4];
  const int b = blockIdx.x, t = threadIdx.x;
  const int w = t >> 6, l = t & 63;
  const int lo = (196*b) >> 5, hi = (196*b + 195) >> 5;
  for (int i = t; i < 320; i += 256){
    float s = 0.f;
    for (int blk = lo; blk <= hi; ++blk){
      int seg = b - (blk*32)/196;
      if (seg >= 0 && seg < 2) s += partialp[blk*640 + seg*320 + i];
    }
    s *= (1.f / 320.f);
    sad[i] = s;
    out_ad[b*320 + i] = s;
  }
  __syncthreads();
  const int c0 = t * 4;
  f32x4 s2v = {0.f,0.f,0.f,0.f};
  const float4* a4 = (const float4*)sad;
#pragma unroll 4
  for (int i = 0; i < 80; ++i){
    float4 sv = a4[i];
    f32x4 w0 = *(const f32x4*)(W2T + (size_t)(4*i  )*1024 + c0);
    f32x4 w1 = *(const f32x4*)(W2T + (size_t)(4*i+1)*1024 + c0);
    f32x4 w2 = *(const f32x4*)(W2T + (size_t)(4*i+2)*1024 + c0);
    f32x4 w3 = *(const f32x4*)(W2T + (size_t)(4*i+3)*1024 + c0);
    s2v += sv.x*w0 + sv.y*w1 + sv.z*w2 + sv.w*w3;
  }
  f32x4 s3v = {0.f,0.f,0.f,0.f};
#pragma unroll
  for (int kg = 0; kg < 16; ++kg)
    s3v += *(const f32x4*)(l3p + (size_t)kg*65536 + b*1024 + c0);
  float l2a[4], l3a[4];
#pragma unroll
  for (int jj = 0; jj < 4; ++jj){
    bool valid = (c0 + jj) < 1000;
    l2a[jj] = valid ? s2v[jj] : -3.4e38f;
    l3a[jj] = valid ? s3v[jj] : -3.4e38f;
  }
  float m2 = fmaxf(fmaxf(l2a[0],l2a[1]), fmaxf(l2a[2],l2a[3]));
  float m3 = fmaxf(fmaxf(l3a[0],l3a[1]), fmaxf(l3a[2],l3a[3]));
#pragma unroll
  for (int off = 32; off > 0; off >>= 1){
    m2 = fmaxf(m2, __shfl_xor(m2, off));
    m3 = fmaxf(m3, __shfl_xor(m3, off));
  }
  if (l == 0){ redA[w] = m2; redB[w] = m3; }
  __syncthreads();
  m2 = fmaxf(fmaxf(redA[0],redA[1]), fmaxf(redA[2],redA[3]));
  m3 = fmaxf(fmaxf(redB[0],redB[1]), fmaxf(redB[2],redB[3]));
  __syncthreads();
  float e2[4], e3[4], s2 = 0.f, s3 = 0.f;
#pragma unroll
  for (int jj = 0; jj < 4; ++jj){
    bool valid = (c0 + jj) < 1000;
    e2[jj] = valid ? __expf(l2a[jj] - m2) : 0.f;
    e3[jj] = valid ? __expf(l3a[jj] - m3) : 0.f;
    s2 += e2[jj]; s3 += e3[jj];
  }
#pragma unroll
  for (int off = 32; off > 0; off >>= 1){
    s2 += __shfl_xor(s2, off);
    s3 += __shfl_xor(s3, off);
  }
  if (l == 0){ redA[w] = s2; redB[w] = s3; }
  __syncthreads();
  s2 = redA[0] + redA[1] + redA[2] + redA[3];
  s3 = redB[0] + redB[1] + redB[2] + redB[3];
  float i2 = 1.f / s2, i3 = 1.f / s3;
#pragma unroll
  for (int jj = 0; jj < 4; ++jj){
    int c = c0 + jj;
    if (c < 1000) outp[b*1000 + c] = 0.5f * (e2[jj]*i2 + e3[jj]*i3);
  }
}

extern "C" void kernel_launch(void* const* d_in, const int* in_sizes, int n_in,
                              void* d_out, int out_size, void* d_ws, size_t ws_size,
                              hipStream_t stream)
{
  const float* attr_map = (const float*)d_in[0];
  const float* features = (const float*)d_in[1];
  const float* W1 = (const float*)d_in[2];
  const float* W2 = (const float*)d_in[3];
  const float* W3 = (const float*)d_in[4];
  float* outp = (float*)d_out;

  char* ws = (char*)d_ws;
  u16*   w1bp    = (u16*)ws;                       // 1,310,720 B
  float* W2T     = (float*)(ws + 1310720);         // 1,310,720 B
  float* partial = (float*)(ws + 2621440);         // 1,003,520 B
  float* l3p     = (float*)(ws + 3624960);         // 4,194,304 B (total 7.8 MB)

  kprep    <<<896, 256, 0, stream>>>(W1, W2, features, W3, w1bp, W2T, l3p);
  k1_main  <<<392, 640, 0, stream>>>(attr_map, w1bp, partial);
  k2c_final<<<64, 256, 0, stream>>>(partial, W2T, l3p, outp, outp + 64000);
}

// Round 11
// 101.259 us; speedup vs baseline: 1.0228x; 1.0228x over previous
//
#include <hip/hip_runtime.h>
#include <hip/hip_bf16.h>

typedef unsigned short u16;
typedef __attribute__((ext_vector_type(8))) short short8;
typedef __attribute__((ext_vector_type(4))) float f32x4;
typedef __attribute__((ext_vector_type(16))) float f32x16;

#define MFMA32(a,b,c) __builtin_amdgcn_mfma_f32_32x32x16_bf16(a,b,c,0,0,0)
#define LGKM_BARRIER() asm volatile("s_waitcnt lgkmcnt(0)\n\ts_barrier" ::: "memory")
#define SB0() __builtin_amdgcn_sched_barrier(0)

__device__ __forceinline__ unsigned pk2(float a, float b){
  float2 f = make_float2(a, b);
  __hip_bfloat162 h = __float22bfloat162_rn(f);     // v_cvt_pk_bf16_f32
  unsigned u; __builtin_memcpy(&u, &h, 4); return u;
}

__device__ __forceinline__ short8 pack8(float4 a, float4 b){
  union { unsigned u[4]; short8 s; } v;
  v.u[0] = pk2(a.x, a.y); v.u[1] = pk2(a.z, a.w);
  v.u[2] = pk2(b.x, b.y); v.u[3] = pk2(b.z, b.w);
  return v.s;
}

// =============== kPrep: W1-permute(32x32 frag) + W2 transpose + GEMM3 =====
// blocks 0..319   : W1 -> w1bp: elem j of gid=(kc*10+nt)*64+l holds
//                   W1[nt*32 + (l&31)][kc*16 + (l>>5)*8 + j]   (B frag order)
// blocks 320..639 : W2[1000][320] -> W2T[320][1024] zero-padded
// blocks 640..895 : l3p[kg(16)][64][1024] = feat @ W3^T split-K partials
__global__ __launch_bounds__(256) void kprep(
    const float* __restrict__ W1, const float* __restrict__ W2,
    const float* __restrict__ feat, const float* __restrict__ W3,
    u16* __restrict__ w1bp, float* __restrict__ W2T, float* __restrict__ l3p)
{
  __shared__ float tile[32][33];
  __shared__ __attribute__((aligned(16))) float At[32*68];
  __shared__ __attribute__((aligned(16))) float Bt[32*68];
  const int bid = blockIdx.x;
  const int t = threadIdx.x;

  if (bid < 320){
    int gid = bid * 256 + t;
    int l = gid & 63;
    int cn = gid >> 6;            // kc*10 + nt, 0..1279
    int kc = cn / 10;
    int nt = cn - kc * 10;
    int row = nt * 32 + (l & 31);
    int col = kc * 16 + (l >> 5) * 8;
    const float4* s = (const float4*)(W1 + (size_t)row * 2048 + col);
    *(short8*)(w1bp + (size_t)gid * 8) = pack8(s[0], s[1]);
  } else if (bid < 640){
    const int bb = bid - 320;
    const int tx = t & 31, ty = t >> 5;          // 32 x 8
    const int bx = bb & 31;                      // c tile (32 -> 1024)
    const int by = bb >> 5;                      // a tile (10 -> 320)
#pragma unroll
    for (int k = 0; k < 4; ++k){
      int c = bx*32 + ty + k*8;
      int a = by*32 + tx;
      tile[ty + k*8][tx] = (c < 1000) ? W2[(size_t)c*320 + a] : 0.f;
    }
    __syncthreads();
#pragma unroll
    for (int k = 0; k < 4; ++k){
      int a = by*32 + ty + k*8;
      int c = bx*32 + tx;
      W2T[(size_t)a*1024 + c] = tile[tx][ty + k*8];
    }
  } else {
    // ---- GEMM3: 64x64 C tile, K chunk 128 (4 stages of 32) ----
    const int bb = bid - 640;
    const int kg = bb & 15;              // K chunk of 128
    const int cg = bb >> 4;              // 16 c-groups of 64
    const int cbase = cg * 64;
    const int tm = t >> 4, tn = t & 15;  // 16x16 threads, 4x4 microtile
    const int sr = t >> 2, skc = (t & 3) * 8;  // staging: row, k-chunk
    f32x4 acc4[4];
#pragma unroll
    for (int i = 0; i < 4; ++i) acc4[i] = (f32x4){0.f,0.f,0.f,0.f};

    for (int st = 0; st < 4; ++st){
      const int kbase = kg*128 + st*32;
      {
        const float4* s = (const float4*)(feat + (size_t)sr*2048 + kbase + skc);
        float4 v0 = s[0], v1 = s[1];
        At[(skc+0)*68 + sr] = v0.x; At[(skc+1)*68 + sr] = v0.y;
        At[(skc+2)*68 + sr] = v0.z; At[(skc+3)*68 + sr] = v0.w;
        At[(skc+4)*68 + sr] = v1.x; At[(skc+5)*68 + sr] = v1.y;
        At[(skc+6)*68 + sr] = v1.z; At[(skc+7)*68 + sr] = v1.w;
      }
      {
        int c = cbase + sr;
        float4 v0 = {0,0,0,0}, v1 = {0,0,0,0};
        if (c < 1000){
          const float4* s = (const float4*)(W3 + (size_t)c*2048 + kbase + skc);
          v0 = s[0]; v1 = s[1];
        }
        Bt[(skc+0)*68 + sr] = v0.x; Bt[(skc+1)*68 + sr] = v0.y;
        Bt[(skc+2)*68 + sr] = v0.z; Bt[(skc+3)*68 + sr] = v0.w;
        Bt[(skc+4)*68 + sr] = v1.x; Bt[(skc+5)*68 + sr] = v1.y;
        Bt[(skc+6)*68 + sr] = v1.z; Bt[(skc+7)*68 + sr] = v1.w;
      }
      __syncthreads();
#pragma unroll
      for (int kk = 0; kk < 32; ++kk){
        f32x4 a = *(const f32x4*)(At + kk*68 + tm*4);
        f32x4 b = *(const f32x4*)(Bt + kk*68 + tn*4);
        acc4[0] += a[0] * b;
        acc4[1] += a[1] * b;
        acc4[2] += a[2] * b;
        acc4[3] += a[3] * b;
      }
      __syncthreads();
    }
#pragma unroll
    for (int i = 0; i < 4; ++i)
      *(f32x4*)(l3p + (size_t)kg*65536 + (tm*4+i)*1024 + cbase + tn*4) = acc4[i];
  }
}

// =============== K1: GEMM1 (32x32 MFMA) + softmax + region partials =======
// grid 392 (M=32), block 640 (10 waves). Wave wv owns n-cols [wv*32, wv*32+32).
// B: direct L2->reg (fragment-ordered w1bp), double reg-buffered, SB0-pinned.
// A: regs -> cvt_pk bf16 -> swizzled LDS dbuf (2 x 4KB). lgkm-only barrier.
__global__ __launch_bounds__(640, 5) void k1_main(
    const float* __restrict__ am, const u16* __restrict__ w1bp,
    float* __restrict__ partial)
{
  __shared__ __attribute__((aligned(16))) u16 sA[2][2048];  // 2 x 4 KB
  __shared__ float redM[32][10];
  __shared__ float redS[32][10];

  const int t = threadIdx.x;
  const int wv = t >> 6, l = t & 63;
  const int half = l >> 5;
  const int rA = l & 31;
  const int blk = blockIdx.x;
  const int phase = (blk * 7) & 31;

  f32x16 acc;
#pragma unroll
  for (int r = 0; r < 16; ++r) acc[r] = 0.f;

  // A staging (threads 0..511): row ar, float4 quad aq of each 64-k chunk
  const int ar = t >> 4, aq = t & 15;
  const float* aptr = am + (size_t)(blk*32 + ar)*2048 + aq*4;
  const int awb = ar*128 + (((aq>>1) ^ (ar & 7))*16) + (aq & 1)*8;

  // B fragment base: chunk c: byte (c*10 + wv)*1024 + l*16
  const char* const bb = (const char*)w1bp + (size_t)wv*1024 + (size_t)l*16;

  // A-frag read offsets (kc = 0..3): row rA, slot (kc*2+half) swizzled
  const int ab0 = rA*128 + (((0*2+half) ^ (rA & 7))*16);
  const int ab1 = rA*128 + (((1*2+half) ^ (rA & 7))*16);
  const int ab2 = rA*128 + (((2*2+half) ^ (rA & 7))*16);
  const int ab3 = rA*128 + (((3*2+half) ^ (rA & 7))*16);

  short8 Be0, Be1, Be2, Be3, Bo0, Bo1, Bo2, Bo3;
  float4 Se, So;

#define LDB(K, S0, S1, S2, S3)                                          \
  { const char* bp = bb + (size_t)(K)*40960;                            \
    S0 = *(const short8*)(bp);                                          \
    S1 = *(const short8*)(bp + 10240);                                  \
    S2 = *(const short8*)(bp + 20480);                                  \
    S3 = *(const short8*)(bp + 30720); }

#define DSW(BUF, S)                                                     \
  if (t < 512){                                                         \
    unsigned p0 = pk2(S.x, S.y);                                        \
    unsigned p1 = pk2(S.z, S.w);                                        \
    *(uint2*)((char*)&sA[BUF][0] + awb) = make_uint2(p0, p1);           \
  }

#define MFMA4(BUF, B0, B1, B2, B3)                                      \
  { const char* sac = (const char*)&sA[BUF][0];                         \
    short8 a0 = *(const short8*)(sac + ab0);                            \
    acc = MFMA32(a0, B0, acc);                                          \
    short8 a1 = *(const short8*)(sac + ab1);                            \
    acc = MFMA32(a1, B1, acc);                                          \
    short8 a2 = *(const short8*)(sac + ab2);                            \
    acc = MFMA32(a2, B2, acc);                                          \
    short8 a3 = *(const short8*)(sac + ab3);                            \
    acc = MFMA32(a3, B3, acc); }

  // ---------------- prologue ----------------
  {
    const int p0 = phase, p1 = (phase + 1) & 31;
    if (t < 512){
      Se = *(const float4*)(aptr + (size_t)p0*64);   // A(0)
      So = *(const float4*)(aptr + (size_t)p1*64);   // A(1)
    }
    DSW(0, Se);                                      // A(0) -> sA[0]
    LDB(p0, Be0, Be1, Be2, Be3);                     // B(0)
    LGKM_BARRIER();
  }

  // ---------------- steady: k = 0..29 (15 pairs) ----------------
#pragma unroll 1
  for (int k2 = 0; k2 < 15; ++k2){
    const int k = 2*k2;
    // even k: compute (sA[0], Be); stage A(k+1)=So; load A(k+2)->Se, B(k+1)->Bo
    {
      const int kpA = (phase + k + 2) & 31;
      const int kpB = (phase + k + 1) & 31;
      if (t < 512) Se = *(const float4*)(aptr + (size_t)kpA*64);
      LDB(kpB, Bo0, Bo1, Bo2, Bo3);
      SB0();                                   // pin: loads issued before below
      DSW(1, So);
      MFMA4(0, Be0, Be1, Be2, Be3);
      LGKM_BARRIER();
    }
    // odd k+1: compute (sA[1], Bo); stage A(k+2)=Se; load A(k+3)->So, B(k+2)->Be
    {
      const int kpA = (phase + k + 3) & 31;
      const int kpB = (phase + k + 2) & 31;
      if (t < 512) So = *(const float4*)(aptr + (size_t)kpA*64);
      LDB(kpB, Be0, Be1, Be2, Be3);
      SB0();
      DSW(0, Se);
      MFMA4(1, Bo0, Bo1, Bo2, Bo3);
      LGKM_BARRIER();
    }
  }
  // ---------------- k = 30 ----------------
  {
    const int kpB = (phase + 31) & 31;
    LDB(kpB, Bo0, Bo1, Bo2, Bo3);
    SB0();
    DSW(1, So);                             // A(31) -> sA[1]
    MFMA4(0, Be0, Be1, Be2, Be3);
    LGKM_BARRIER();
  }
  // ---------------- k = 31 ----------------
  MFMA4(1, Bo0, Bo1, Bo2, Bo3);

#undef LDB
#undef DSW
#undef MFMA4

  // ---- epilogue: softmax over 320 cols ----
  // C/D: col(n) = wv*32 + (l&31); row = (r&3) + 8*(r>>2) + 4*half
  {
    float rmx[16];
#pragma unroll
    for (int r = 0; r < 16; ++r){
      float x = acc[r];
      x = fmaxf(x, __shfl_xor(x, 1));
      x = fmaxf(x, __shfl_xor(x, 2));
      x = fmaxf(x, __shfl_xor(x, 4));
      x = fmaxf(x, __shfl_xor(x, 8));
      x = fmaxf(x, __shfl_xor(x, 16));
      rmx[r] = x;
    }
    if ((l & 31) == 0){
#pragma unroll
      for (int r = 0; r < 16; ++r)
        redM[(r&3) + 8*(r>>2) + 4*half][wv] = rmx[r];
    }
  }
  __syncthreads();
  if (wv == 0 && l < 32){
    float m = redM[l][0];
#pragma unroll
    for (int w2 = 1; w2 < 10; ++w2) m = fmaxf(m, redM[l][w2]);
    redM[l][0] = m;
  }
  __syncthreads();
  {
    float rsum[16];
#pragma unroll
    for (int r = 0; r < 16; ++r){
      int row = (r&3) + 8*(r>>2) + 4*half;
      float e = __expf(acc[r] - redM[row][0]);
      acc[r] = e;
      float s = e;
      s += __shfl_xor(s, 1);
      s += __shfl_xor(s, 2);
      s += __shfl_xor(s, 4);
      s += __shfl_xor(s, 8);
      s += __shfl_xor(s, 16);
      rsum[r] = s;
    }
    if ((l & 31) == 0){
#pragma unroll
      for (int r = 0; r < 16; ++r)
        redS[(r&3) + 8*(r>>2) + 4*half][wv] = rsum[r];
    }
  }
  __syncthreads();
  if (wv == 0 && l < 32){
    float s = 0.f;
#pragma unroll
    for (int w2 = 0; w2 < 10; ++w2) s += redS[l][w2];
    redS[l][0] = 1.f / s;
  }
  __syncthreads();
  {
    const int n0 = blk * 32;
    const int thr = 196 * (n0/196 + 1) - n0;   // rows < thr -> seg0
    float s0 = 0.f, s1 = 0.f;
#pragma unroll
    for (int r = 0; r < 16; ++r){
      int row = (r&3) + 8*(r>>2) + 4*half;
      float v = acc[r] * redS[row][0];
      if (row < thr) s0 += v; else s1 += v;
    }
    s0 += __shfl_xor(s0, 32);
    s1 += __shfl_xor(s1, 32);
    if (l < 32){
      partial[blk*640 +       wv*32 + l] = s0;
      partial[blk*640 + 320 + wv*32 + l] = s1;
    }
  }
}

// =============== K2c: reduce partials + attr_dis@W2T + both softmax =======
__global__ __launch_bounds__(256) void k2c_final(
    const float* __restrict__ partialp, const float* __restrict__ W2T,
    const float* __restrict__ l3p, float* __restrict__ outp,
    float* __restrict__ out_ad)
{
  __shared__ __attribute__((aligned(16))) float sad[320];
  __shared__ float redA[4], redB[4];
  const int b = blockIdx.x, t = threadIdx.x;
  const int w = t >> 6, l = t & 63;
  const int lo = (196*b) >> 5, hi = (196*b + 195) >> 5;
  for (int i = t; i < 320; i += 256){
    float s = 0.f;
    for (int blk = lo; blk <= hi; ++blk){
      int seg = b - (blk*32)/196;
      if (seg >= 0 && seg < 2) s += partialp[blk*640 + seg*320 + i];
    }
    s *= (1.f / 320.f);
    sad[i] = s;
    out_ad[b*320 + i] = s;
  }
  __syncthreads();
  const int c0 = t * 4;
  f32x4 s2v = {0.f,0.f,0.f,0.f};
  const float4* a4 = (const float4*)sad;
#pragma unroll 4
  for (int i = 0; i < 80; ++i){
    float4 sv = a4[i];
    f32x4 w0 = *(const f32x4*)(W2T + (size_t)(4*i  )*1024 + c0);
    f32x4 w1 = *(const f32x4*)(W2T + (size_t)(4*i+1)*1024 + c0);
    f32x4 w2 = *(const f32x4*)(W2T + (size_t)(4*i+2)*1024 + c0);
    f32x4 w3 = *(const f32x4*)(W2T + (size_t)(4*i+3)*1024 + c0);
    s2v += sv.x*w0 + sv.y*w1 + sv.z*w2 + sv.w*w3;
  }
  f32x4 s3v = {0.f,0.f,0.f,0.f};
#pragma unroll
  for (int kg = 0; kg < 16; ++kg)
    s3v += *(const f32x4*)(l3p + (size_t)kg*65536 + b*1024 + c0);
  float l2a[4], l3a[4];
#pragma unroll
  for (int jj = 0; jj < 4; ++jj){
    bool valid = (c0 + jj) < 1000;
    l2a[jj] = valid ? s2v[jj] : -3.4e38f;
    l3a[jj] = valid ? s3v[jj] : -3.4e38f;
  }
  float m2 = fmaxf(fmaxf(l2a[0],l2a[1]), fmaxf(l2a[2],l2a[3]));
  float m3 = fmaxf(fmaxf(l3a[0],l3a[1]), fmaxf(l3a[2],l3a[3]));
#pragma unroll
  for (int off = 32; off > 0; off >>= 1){
    m2 = fmaxf(m2, __shfl_xor(m2, off));
    m3 = fmaxf(m3, __shfl_xor(m3, off));
  }
  if (l == 0){ redA[w] = m2; redB[w] = m3; }
  __syncthreads();
  m2 = fmaxf(fmaxf(redA[0],redA[1]), fmaxf(redA[2],redA[3]));
  m3 = fmaxf(fmaxf(redB[0],redB[1]), fmaxf(redB[2],redB[3]));
  __syncthreads();
  float e2[4], e3[4], s2 = 0.f, s3 = 0.f;
#pragma unroll
  for (int jj = 0; jj < 4; ++jj){
    bool valid = (c0 + jj) < 1000;
    e2[jj] = valid ? __expf(l2a[jj] - m2) : 0.f;
    e3[jj] = valid ? __expf(l3a[jj] - m3) : 0.f;
    s2 += e2[jj]; s3 += e3[jj];
  }
#pragma unroll
  for (int off = 32; off > 0; off >>= 1){
    s2 += __shfl_xor(s2, off);
    s3 += __shfl_xor(s3, off);
  }
  if (l == 0){ redA[w] = s2; redB[w] = s3; }
  __syncthreads();
  s2 = redA[0] + redA[1] + redA[2] + redA[3];
  s3 = redB[0] + redB[1] + redB[2] + redB[3];
  float i2 = 1.f / s2, i3 = 1.f / s3;
#pragma unroll
  for (int jj = 0; jj < 4; ++jj){
    int c = c0 + jj;
    if (c < 1000) outp[b*1000 + c] = 0.5f * (e2[jj]*i2 + e3[jj]*i3);
  }
}

extern "C" void kernel_launch(void* const* d_in, const int* in_sizes, int n_in,
                              void* d_out, int out_size, void* d_ws, size_t ws_size,
                              hipStream_t stream)
{
  const float* attr_map = (const float*)d_in[0];
  const float* features = (const float*)d_in[1];
  const float* W1 = (const float*)d_in[2];
  const float* W2 = (const float*)d_in[3];
  const float* W3 = (const float*)d_in[4];
  float* outp = (float*)d_out;

  char* ws = (char*)d_ws;
  u16*   w1bp    = (u16*)ws;                       // 1,310,720 B
  float* W2T     = (float*)(ws + 1310720);         // 1,310,720 B
  float* partial = (float*)(ws + 2621440);         // 1,003,520 B
  float* l3p     = (float*)(ws + 3624960);         // 4,194,304 B (total 7.8 MB)

  kprep    <<<896, 256, 0, stream>>>(W1, W2, features, W3, w1bp, W2T, l3p);
  k1_main  <<<392, 640, 0, stream>>>(attr_map, w1bp, partial);
  k2c_final<<<64, 256, 0, stream>>>(partial, W2T, l3p, outp, outp + 64000);
}